// Round 18
// baseline (78.235 us; speedup 1.0000x reference)
//
#include <hip/hip_runtime.h>

#define NN 50000
#define NEG_SLOPE 0.2f
#define LOG2E 1.44269504088896340736f

#define GEMM_NB ((NN + 63) / 64)    // 782 gemm blocks
#define NBUCK 196                   // buckets of 256 rows
#define EPB 4096                    // edges per scatter block (196 blocks @ E=800K)
#define CAPF 4608                   // full-bucket LDS cap (mean 4081, +8 sigma)
#define CAPH 2816                   // half-bucket sorted cap (mean 2040, +17 sigma)

typedef __bf16 bf16x8 __attribute__((ext_vector_type(8)));
typedef float f32x4 __attribute__((ext_vector_type(4)));

static __device__ __forceinline__ unsigned short f2bf(float f) {
    __bf16 b = (__bf16)f;
    return __builtin_bit_cast(unsigned short, b);
}
static __device__ __forceinline__ float bf2f(unsigned short u) {
    return __uint_as_float(((unsigned)u) << 16);
}

// Per-wave int64-vs-int32 detection: values < 50000, so int64 => all odd
// int32 words of the first 64 pairs are zero. (L1-hit, ~free per wave.)
static __device__ __forceinline__ int detect_i64(const int* __restrict__ ei,
                                                 int lane) {
    unsigned long long b = __ballot(ei[2 * lane + 1] != 0);
    return (b == 0ull) ? 1 : 0;
}

// ---------------------------------------------------------------------------
// FUSED0 (unchanged from r16, proven): blocks [0, GEMM_NB): MFMA GEMM;
// blocks [GEMM_NB, GEMM_NB+NB1): per-block edge LDS counting sort; sorted
// slice written CONTIGUOUSLY to tmp[bx*EPB..] + S/LP matrices. No global
// atomics, no memsets.
__global__ __launch_bounds__(256) void k_fused0(
        const float* __restrict__ x, const float* __restrict__ W,
        const float* __restrict__ sa, const float* __restrict__ da,
        const int* __restrict__ ei,
        unsigned short* __restrict__ hb, float* __restrict__ s,
        float* __restrict__ d, int* __restrict__ S, int* __restrict__ LP,
        unsigned* __restrict__ tmp, int E, int NB1) {
    __shared__ int hist[256];       // bucket counts -> cursors
    __shared__ int pref[256];       // inclusive scan
    __shared__ unsigned lrec[EPB];  // block-locally sorted records (16 KB)
    const int tid  = threadIdx.x;
    const int lane = tid & 63;

    if (blockIdx.x >= GEMM_NB) {
        // ---- bucket-sort path (EPB = 4096 edges/block, 16/thread) ----
        const int bx = blockIdx.x - GEMM_NB;
        hist[tid] = 0;
        const int f = detect_i64(ei, lane);
        __syncthreads();

        const int base = bx * EPB + tid * 16;
        int rw[16], cl[16];
        const bool fullvec = (base + 16 <= E) && ((E & 3) == 0);
        if (f) {
            if (fullvec) {
                const int4* p = (const int4*)(ei + 2 * base);
                const int4* q = (const int4*)(ei + 2 * E + 2 * base);
                #pragma unroll
                for (int g = 0; g < 8; ++g) {
                    int4 a = p[g]; int4 b = q[g];
                    rw[2 * g] = a.x; rw[2 * g + 1] = a.z;
                    cl[2 * g] = b.x; cl[2 * g + 1] = b.z;
                }
            } else {
                #pragma unroll
                for (int k = 0; k < 16; ++k) {
                    int e = base + k;
                    rw[k] = (e < E) ? ei[2 * e] : -1;
                    cl[k] = (e < E) ? ei[2 * E + 2 * e] : 0;
                }
            }
        } else {
            if (fullvec) {
                const int4* p = (const int4*)(ei + base);
                const int4* q = (const int4*)(ei + E + base);
                #pragma unroll
                for (int g = 0; g < 4; ++g) {
                    int4 a = p[g]; int4 b = q[g];
                    rw[4 * g] = a.x; rw[4 * g + 1] = a.y;
                    rw[4 * g + 2] = a.z; rw[4 * g + 3] = a.w;
                    cl[4 * g] = b.x; cl[4 * g + 1] = b.y;
                    cl[4 * g + 2] = b.z; cl[4 * g + 3] = b.w;
                }
            } else {
                #pragma unroll
                for (int k = 0; k < 16; ++k) {
                    int e = base + k;
                    rw[k] = (e < E) ? ei[e] : -1;
                    cl[k] = (e < E) ? ei[E + e] : 0;
                }
            }
        }

        #pragma unroll
        for (int k = 0; k < 16; ++k)
            if (rw[k] >= 0) atomicAdd(&hist[rw[k] >> 8], 1);
        __syncthreads();

        const int myCnt = hist[tid];
        pref[tid] = myCnt;
        __syncthreads();
        for (int off = 1; off < 256; off <<= 1) {
            int u = (tid >= off) ? pref[tid - off] : 0;
            __syncthreads();
            pref[tid] += u;
            __syncthreads();
        }
        if (tid < NBUCK) {
            S[tid * NB1 + bx]  = myCnt;             // count of bucket-tid records
            LP[tid * NB1 + bx] = pref[tid] - myCnt; // start within this slice
        }
        hist[tid] = pref[tid] - myCnt;              // local cursor
        __syncthreads();

        #pragma unroll
        for (int k = 0; k < 16; ++k) {
            if (rw[k] >= 0) {
                int lp = atomicAdd(&hist[rw[k] >> 8], 1);
                lrec[lp] = ((unsigned)(rw[k] & 255) << 24) | (unsigned)cl[k];
            }
        }
        __syncthreads();

        const int tot = pref[255];
        for (int j = tid; j < tot; j += 256)
            tmp[bx * EPB + j] = lrec[j];
        return;
    }

    // ---- gemm path (unchanged, proven) ----
    const int wave = tid >> 6;
    const int c    = lane & 15;   // A-row / B-col / C-col within tile
    const int kg   = lane >> 4;   // 0..3 k-group
    const int n0   = blockIdx.x * 64 + wave * 16;

    bf16x8 bf[4][4];
    #pragma unroll
    for (int kt = 0; kt < 4; ++kt) {
        #pragma unroll
        for (int ot = 0; ot < 4; ++ot) {
            const float* wp = &W[(ot * 16 + c) * 128 + kt * 32 + kg * 8];
            f32x4 w0 = *(const f32x4*)wp;
            f32x4 w1 = *(const f32x4*)(wp + 4);
            bf16x8 b;
            #pragma unroll
            for (int j = 0; j < 4; ++j) { b[j] = (__bf16)w0[j]; b[4 + j] = (__bf16)w1[j]; }
            bf[kt][ot] = b;
        }
    }

    int nr = n0 + c; if (nr > NN - 1) nr = NN - 1;
    const float* xp = &x[(long)nr * 128 + kg * 8];

    f32x4 acc[4] = {};
    #pragma unroll
    for (int kt = 0; kt < 4; ++kt) {
        f32x4 x0 = *(const f32x4*)(xp + kt * 32);
        f32x4 x1 = *(const f32x4*)(xp + kt * 32 + 4);
        bf16x8 a;
        #pragma unroll
        for (int j = 0; j < 4; ++j) { a[j] = (__bf16)x0[j]; a[4 + j] = (__bf16)x1[j]; }
        #pragma unroll
        for (int ot = 0; ot < 4; ++ot)
            acc[ot] = __builtin_amdgcn_mfma_f32_16x16x32_bf16(a, bf[kt][ot], acc[ot], 0, 0, 0);
    }

    float sav[4], dav[4];
    #pragma unroll
    for (int ot = 0; ot < 4; ++ot) {
        sav[ot] = sa[ot * 16 + c] * LOG2E;
        dav[ot] = da[ot * 16 + c] * LOG2E;
    }

    const int nodebase = n0 + kg * 4;
    #pragma unroll
    for (int r = 0; r < 4; ++r) {
        const int n = nodebase + r;
        const bool ok = (n < NN);
        if (ok) {
            #pragma unroll
            for (int ot = 0; ot < 4; ++ot) hb[n * 64 + ot * 16 + c] = f2bf(acc[ot][r]);
        }
        float ps[4], pd[4];
        #pragma unroll
        for (int ot = 0; ot < 4; ++ot) { ps[ot] = acc[ot][r] * sav[ot]; pd[ot] = acc[ot][r] * dav[ot]; }
        #pragma unroll
        for (int m = 1; m < 8; m <<= 1) {
            #pragma unroll
            for (int ot = 0; ot < 4; ++ot) {
                ps[ot] += __shfl_xor(ps[ot], m, 64);
                pd[ot] += __shfl_xor(pd[ot], m, 64);
            }
        }
        if (ok && (c & 7) == 0) {
            const int hbid = c >> 3;
            #pragma unroll
            for (int ot = 0; ot < 4; ++ot) {
                s[n * 8 + 2 * ot + hbid] = ps[ot];
                d[n * 8 + 2 * ot + hbid] = pd[ot];
            }
        }
    }
}

// ---------------------------------------------------------------------------
// k_bgather: 2 blocks per bucket (halves of 128 rows), 1024 threads.
// Stage: PARALLEL binary-search staging — thread p finds its source slice in
// 8 LDS steps and copies one record (no idle lanes). Sort: half-filtered
// 128-bin LDS counting sort. Gather: wave-uniform per-edge loop — c from LDS
// broadcast, per-lane d load (32B), one exp2 per edge, per-lane dsum IS the
// denominator (no cross-lane reduce, no divergent tail). unroll 4 -> 4
// independent load chains in flight.
__global__ __launch_bounds__(1024) void k_bgather(
        const unsigned* __restrict__ tmp, const int* __restrict__ S,
        const int* __restrict__ LP, const unsigned short* __restrict__ hb,
        const float* __restrict__ sarr, const float* __restrict__ d,
        float* __restrict__ out, int NB1) {
    __shared__ int aux2[256];        // inclusive scan of per-source counts
    __shared__ int aux3[256];        // LP per source block
    __shared__ int bins[128];
    __shared__ int pref2[128];
    __shared__ unsigned u_raw[CAPF];
    __shared__ int lcol[CAPH];

    const int t    = threadIdx.x;
    const int bkt  = blockIdx.x >> 1;
    const int half = blockIdx.x & 1;
    const int lane = t & 63;
    const int wid  = t >> 6;

    if (t < 256) {
        aux2[t] = (t < NB1) ? S[bkt * NB1 + t] : 0;
        aux3[t] = (t < NB1) ? LP[bkt * NB1 + t] : 0;
    }
    __syncthreads();
    for (int off = 1; off < 256; off <<= 1) {
        int u = 0;
        if (t < 256 && t >= off) u = aux2[t - off];
        __syncthreads();
        if (t < 256) aux2[t] += u;
        __syncthreads();
    }
    int cnt = aux2[255]; if (cnt > CAPF) cnt = CAPF;

    // parallel staging via binary search over the inclusive scan
    for (int p = t; p < cnt; p += 1024) {
        int lo = 0, hi = 255;          // first bx with aux2[bx] > p
        #pragma unroll
        for (int it = 0; it < 8; ++it) {
            const int mid = (lo + hi) >> 1;
            if (aux2[mid] > p) hi = mid; else lo = mid + 1;
        }
        const int excl = lo ? aux2[lo - 1] : 0;
        u_raw[p] = tmp[lo * EPB + aux3[lo] + (p - excl)];
    }
    __syncthreads();

    // half-filtered row sort (128 bins; rows [half*128, half*128+128))
    if (t < 128) bins[t] = 0;
    __syncthreads();
    for (int i = t; i < cnt; i += 1024) {
        const int r8 = (int)(u_raw[i] >> 24);
        if ((r8 >> 7) == half) atomicAdd(&bins[r8 & 127], 1);
    }
    __syncthreads();
    const int bv = (t < 128) ? bins[t] : 0;
    if (t < 128) pref2[t] = bv;
    __syncthreads();
    for (int off = 1; off < 128; off <<= 1) {
        int u = 0;
        if (t < 128 && t >= off) u = pref2[t - off];
        __syncthreads();
        if (t < 128) pref2[t] += u;
        __syncthreads();
    }
    if (t < 128) bins[t] = pref2[t] - bv;   // exclusive -> cursors
    __syncthreads();
    for (int i = t; i < cnt; i += 1024) {
        const unsigned v = u_raw[i];
        const int r8 = (int)(v >> 24);
        if ((r8 >> 7) == half) {
            const int p = atomicAdd(&bins[r8 & 127], 1);
            if (p < CAPH) lcol[p] = (int)(v & 0xFFFFu);
        }
    }
    __syncthreads();

    // gather: 128 rows, 8 per wave; wave-uniform per-edge loop.
    const int o  = lane;
    const int oh = o >> 3;

    #pragma unroll
    for (int j = 0; j < 8; ++j) {
        const int rl = j * 16 + wid;             // 0..127 within half
        const int n  = bkt * 256 + half * 128 + rl;
        if (n >= NN) continue;

        const int bgn = rl ? pref2[rl - 1] : 0;
        const int end = pref2[rl];

        const float sn_o = sarr[n * 8 + oh];
        const float dn_o = d[n * 8 + oh];
        float acc  = 0.0f;
        float dsum = 0.0f;

        #pragma unroll 4
        for (int i = bgn; i < end; ++i) {
            const int c = lcol[i];               // wave-uniform LDS broadcast
            float v = sn_o + d[c * 8 + oh];      // 32B lane-shared gather
            v = fmaxf(v, NEG_SLOPE * v);
            const float ev = __builtin_amdgcn_exp2f(v);
            dsum += ev;
            acc += ev * bf2f(hb[c * 64 + o]);    // 128B line-pair gather
        }

        // self loop; per-lane dsum is already the head-oh denominator
        float vs = sn_o + dn_o;
        vs = fmaxf(vs, NEG_SLOPE * vs);
        const float es = __builtin_amdgcn_exp2f(vs);
        out[n * 64 + o] = (acc + es * bf2f(hb[n * 64 + o])) / (dsum + es);
    }
}

// ---------------------------------------------------------------------------
extern "C" void kernel_launch(void* const* d_in, const int* in_sizes, int n_in,
                              void* d_out, int out_size, void* d_ws, size_t ws_size,
                              hipStream_t stream) {
    const float* x  = (const float*)d_in[0];
    const int*   ei = (const int*)d_in[1];
    const float* W  = (const float*)d_in[2];
    const float* sa = (const float*)d_in[3];
    const float* da = (const float*)d_in[4];
    float* out = (float*)d_out;
    const int E = in_sizes[1] / 2;

    int NB1 = (E + EPB - 1) / EPB;         // 196 at E=800000
    if (NB1 > 256) NB1 = 256;              // scan width bound (holds for this shape)

    // ws layout
    unsigned short* hb = (unsigned short*)d_ws;     // NN*64 bf16 (6.4 MB)
    float* s  = (float*)(hb + NN * 64);             // NN*8
    float* dd = s + NN * 8;                         // NN*8
    int* S    = (int*)(dd + NN * 8);                // NBUCK*NB1
    int* LP   = S + NBUCK * 256;                    // NBUCK*NB1
    unsigned* tmp = (unsigned*)(LP + NBUCK * 256);  // NB1*EPB (3.2 MB)

    k_fused0<<<GEMM_NB + NB1, 256, 0, stream>>>(x, W, sa, da, ei,
                                                hb, s, dd, S, LP, tmp, E, NB1);
    k_bgather<<<NBUCK * 2, 1024, 0, stream>>>(tmp, S, LP, hb, s, dd, out, NB1);
}

// Round 19
// 68.851 us; speedup vs baseline: 1.1363x; 1.1363x over previous
//
#include <hip/hip_runtime.h>

#define NN 50000
#define NEG_SLOPE 0.2f
#define LOG2E 1.44269504088896340736f

#define GEMM_NB ((NN + 63) / 64)    // 782 gemm blocks
#define NBUCK 196                   // buckets of 256 rows
#define EPB 4096                    // edges per scatter block (196 blocks @ E=800K)
#define CAPF 4608                   // full-bucket LDS cap (mean 4081, +8 sigma)
#define CAPH 2816                   // half-bucket sorted cap (mean 2040, +17 sigma)

typedef __bf16 bf16x8 __attribute__((ext_vector_type(8)));
typedef float f32x4 __attribute__((ext_vector_type(4)));

static __device__ __forceinline__ unsigned short f2bf(float f) {
    __bf16 b = (__bf16)f;
    return __builtin_bit_cast(unsigned short, b);
}
static __device__ __forceinline__ float bf2f(unsigned short u) {
    return __uint_as_float(((unsigned)u) << 16);
}

// Per-wave int64-vs-int32 detection: values < 50000, so int64 => all odd
// int32 words of the first 64 pairs are zero. (L1-hit, ~free per wave.)
static __device__ __forceinline__ int detect_i64(const int* __restrict__ ei,
                                                 int lane) {
    unsigned long long b = __ballot(ei[2 * lane + 1] != 0);
    return (b == 0ull) ? 1 : 0;
}

// ---------------------------------------------------------------------------
// FUSED0 (unchanged, proven): blocks [0, GEMM_NB): MFMA GEMM;
// blocks [GEMM_NB, GEMM_NB+NB1): per-block edge LDS counting sort; sorted
// slice written CONTIGUOUSLY to tmp[bx*EPB..] + S/LP matrices. No global
// atomics, no memsets.
__global__ __launch_bounds__(256) void k_fused0(
        const float* __restrict__ x, const float* __restrict__ W,
        const float* __restrict__ sa, const float* __restrict__ da,
        const int* __restrict__ ei,
        unsigned short* __restrict__ hb, float* __restrict__ s,
        float* __restrict__ d, int* __restrict__ S, int* __restrict__ LP,
        unsigned* __restrict__ tmp, int E, int NB1) {
    __shared__ int hist[256];       // bucket counts -> cursors
    __shared__ int pref[256];       // inclusive scan
    __shared__ unsigned lrec[EPB];  // block-locally sorted records (16 KB)
    const int tid  = threadIdx.x;
    const int lane = tid & 63;

    if (blockIdx.x >= GEMM_NB) {
        // ---- bucket-sort path (EPB = 4096 edges/block, 16/thread) ----
        const int bx = blockIdx.x - GEMM_NB;
        hist[tid] = 0;
        const int f = detect_i64(ei, lane);
        __syncthreads();

        const int base = bx * EPB + tid * 16;
        int rw[16], cl[16];
        const bool fullvec = (base + 16 <= E) && ((E & 3) == 0);
        if (f) {
            if (fullvec) {
                const int4* p = (const int4*)(ei + 2 * base);
                const int4* q = (const int4*)(ei + 2 * E + 2 * base);
                #pragma unroll
                for (int g = 0; g < 8; ++g) {
                    int4 a = p[g]; int4 b = q[g];
                    rw[2 * g] = a.x; rw[2 * g + 1] = a.z;
                    cl[2 * g] = b.x; cl[2 * g + 1] = b.z;
                }
            } else {
                #pragma unroll
                for (int k = 0; k < 16; ++k) {
                    int e = base + k;
                    rw[k] = (e < E) ? ei[2 * e] : -1;
                    cl[k] = (e < E) ? ei[2 * E + 2 * e] : 0;
                }
            }
        } else {
            if (fullvec) {
                const int4* p = (const int4*)(ei + base);
                const int4* q = (const int4*)(ei + E + base);
                #pragma unroll
                for (int g = 0; g < 4; ++g) {
                    int4 a = p[g]; int4 b = q[g];
                    rw[4 * g] = a.x; rw[4 * g + 1] = a.y;
                    rw[4 * g + 2] = a.z; rw[4 * g + 3] = a.w;
                    cl[4 * g] = b.x; cl[4 * g + 1] = b.y;
                    cl[4 * g + 2] = b.z; cl[4 * g + 3] = b.w;
                }
            } else {
                #pragma unroll
                for (int k = 0; k < 16; ++k) {
                    int e = base + k;
                    rw[k] = (e < E) ? ei[e] : -1;
                    cl[k] = (e < E) ? ei[E + e] : 0;
                }
            }
        }

        #pragma unroll
        for (int k = 0; k < 16; ++k)
            if (rw[k] >= 0) atomicAdd(&hist[rw[k] >> 8], 1);
        __syncthreads();

        const int myCnt = hist[tid];
        pref[tid] = myCnt;
        __syncthreads();
        for (int off = 1; off < 256; off <<= 1) {
            int u = (tid >= off) ? pref[tid - off] : 0;
            __syncthreads();
            pref[tid] += u;
            __syncthreads();
        }
        if (tid < NBUCK) {
            S[tid * NB1 + bx]  = myCnt;             // count of bucket-tid records
            LP[tid * NB1 + bx] = pref[tid] - myCnt; // start within this slice
        }
        hist[tid] = pref[tid] - myCnt;              // local cursor
        __syncthreads();

        #pragma unroll
        for (int k = 0; k < 16; ++k) {
            if (rw[k] >= 0) {
                int lp = atomicAdd(&hist[rw[k] >> 8], 1);
                lrec[lp] = ((unsigned)(rw[k] & 255) << 24) | (unsigned)cl[k];
            }
        }
        __syncthreads();

        const int tot = pref[255];
        for (int j = tid; j < tot; j += 256)
            tmp[bx * EPB + j] = lrec[j];
        return;
    }

    // ---- gemm path (unchanged, proven) ----
    const int wave = tid >> 6;
    const int c    = lane & 15;   // A-row / B-col / C-col within tile
    const int kg   = lane >> 4;   // 0..3 k-group
    const int n0   = blockIdx.x * 64 + wave * 16;

    bf16x8 bf[4][4];
    #pragma unroll
    for (int kt = 0; kt < 4; ++kt) {
        #pragma unroll
        for (int ot = 0; ot < 4; ++ot) {
            const float* wp = &W[(ot * 16 + c) * 128 + kt * 32 + kg * 8];
            f32x4 w0 = *(const f32x4*)wp;
            f32x4 w1 = *(const f32x4*)(wp + 4);
            bf16x8 b;
            #pragma unroll
            for (int j = 0; j < 4; ++j) { b[j] = (__bf16)w0[j]; b[4 + j] = (__bf16)w1[j]; }
            bf[kt][ot] = b;
        }
    }

    int nr = n0 + c; if (nr > NN - 1) nr = NN - 1;
    const float* xp = &x[(long)nr * 128 + kg * 8];

    f32x4 acc[4] = {};
    #pragma unroll
    for (int kt = 0; kt < 4; ++kt) {
        f32x4 x0 = *(const f32x4*)(xp + kt * 32);
        f32x4 x1 = *(const f32x4*)(xp + kt * 32 + 4);
        bf16x8 a;
        #pragma unroll
        for (int j = 0; j < 4; ++j) { a[j] = (__bf16)x0[j]; a[4 + j] = (__bf16)x1[j]; }
        #pragma unroll
        for (int ot = 0; ot < 4; ++ot)
            acc[ot] = __builtin_amdgcn_mfma_f32_16x16x32_bf16(a, bf[kt][ot], acc[ot], 0, 0, 0);
    }

    float sav[4], dav[4];
    #pragma unroll
    for (int ot = 0; ot < 4; ++ot) {
        sav[ot] = sa[ot * 16 + c] * LOG2E;
        dav[ot] = da[ot * 16 + c] * LOG2E;
    }

    const int nodebase = n0 + kg * 4;
    #pragma unroll
    for (int r = 0; r < 4; ++r) {
        const int n = nodebase + r;
        const bool ok = (n < NN);
        if (ok) {
            #pragma unroll
            for (int ot = 0; ot < 4; ++ot) hb[n * 64 + ot * 16 + c] = f2bf(acc[ot][r]);
        }
        float ps[4], pd[4];
        #pragma unroll
        for (int ot = 0; ot < 4; ++ot) { ps[ot] = acc[ot][r] * sav[ot]; pd[ot] = acc[ot][r] * dav[ot]; }
        #pragma unroll
        for (int m = 1; m < 8; m <<= 1) {
            #pragma unroll
            for (int ot = 0; ot < 4; ++ot) {
                ps[ot] += __shfl_xor(ps[ot], m, 64);
                pd[ot] += __shfl_xor(pd[ot], m, 64);
            }
        }
        if (ok && (c & 7) == 0) {
            const int hbid = c >> 3;
            #pragma unroll
            for (int ot = 0; ot < 4; ++ot) {
                s[n * 8 + 2 * ot + hbid] = ps[ot];
                d[n * 8 + 2 * ot + hbid] = pd[ot];
            }
        }
    }
}

// ---------------------------------------------------------------------------
// k_bgather (r16 structure + parallel staging): 2 blocks per bucket (halves
// of 128 rows), 1024 threads. Stage: thread p binary-searches its source
// slice in 8 LDS steps and copies exactly one record (no idle lanes).
// Sort: half-filtered 128-bin LDS counting sort. Gather: proven (eidx,h)
// chunk-of-8 layout — ONE exp issue per 8 edges x 8 heads, col broadcast via
// readlane, exp via shfl, register accumulation, butterfly denominator.
__global__ __launch_bounds__(1024) void k_bgather(
        const unsigned* __restrict__ tmp, const int* __restrict__ S,
        const int* __restrict__ LP, const unsigned short* __restrict__ hb,
        const float* __restrict__ sarr, const float* __restrict__ d,
        float* __restrict__ out, int NB1) {
    __shared__ int aux2[256];        // inclusive scan of per-source counts
    __shared__ int aux3[256];        // LP per source block
    __shared__ int bins[128];
    __shared__ int pref2[128];
    __shared__ unsigned u_raw[CAPF];
    __shared__ int lcol[CAPH];

    const int t    = threadIdx.x;
    const int bkt  = blockIdx.x >> 1;
    const int half = blockIdx.x & 1;
    const int lane = t & 63;
    const int wid  = t >> 6;

    if (t < 256) {
        aux2[t] = (t < NB1) ? S[bkt * NB1 + t] : 0;
        aux3[t] = (t < NB1) ? LP[bkt * NB1 + t] : 0;
    }
    __syncthreads();
    for (int off = 1; off < 256; off <<= 1) {
        int u = 0;
        if (t < 256 && t >= off) u = aux2[t - off];
        __syncthreads();
        if (t < 256) aux2[t] += u;
        __syncthreads();
    }
    int cnt = aux2[255]; if (cnt > CAPF) cnt = CAPF;

    // parallel staging: thread p binary-searches the source slice owning
    // destination p (first bx with aux2[bx] > p), copies one record.
    for (int p = t; p < cnt; p += 1024) {
        int lo = 0, hi = 255;
        #pragma unroll
        for (int it = 0; it < 8; ++it) {
            const int mid = (lo + hi) >> 1;
            if (aux2[mid] > p) hi = mid; else lo = mid + 1;
        }
        const int excl = lo ? aux2[lo - 1] : 0;
        u_raw[p] = tmp[lo * EPB + aux3[lo] + (p - excl)];
    }
    __syncthreads();

    // half-filtered row sort (128 bins; rows [half*128, half*128+128))
    if (t < 128) bins[t] = 0;
    __syncthreads();
    for (int i = t; i < cnt; i += 1024) {
        const int r8 = (int)(u_raw[i] >> 24);
        if ((r8 >> 7) == half) atomicAdd(&bins[r8 & 127], 1);
    }
    __syncthreads();
    const int bv = (t < 128) ? bins[t] : 0;
    if (t < 128) pref2[t] = bv;
    __syncthreads();
    for (int off = 1; off < 128; off <<= 1) {
        int u = 0;
        if (t < 128 && t >= off) u = pref2[t - off];
        __syncthreads();
        if (t < 128) pref2[t] += u;
        __syncthreads();
    }
    if (t < 128) bins[t] = pref2[t] - bv;   // exclusive -> cursors
    __syncthreads();
    for (int i = t; i < cnt; i += 1024) {
        const unsigned v = u_raw[i];
        const int r8 = (int)(v >> 24);
        if ((r8 >> 7) == half) {
            const int p = atomicAdd(&bins[r8 & 127], 1);
            if (p < CAPH) lcol[p] = (int)(v & 0xFFFFu);
        }
    }
    __syncthreads();

    // gather: 128 rows, 8 per wave; lane = eidx*8 + h over chunks of 8 edges.
    const int o    = lane;
    const int oh   = o >> 3;
    const int eidx = lane >> 3;
    const int h    = lane & 7;

    #pragma unroll
    for (int j = 0; j < 8; ++j) {
        const int rl = j * 16 + wid;             // 0..127 within half
        const int n  = bkt * 256 + half * 128 + rl;
        if (n >= NN) continue;

        const int bgn = rl ? pref2[rl - 1] : 0;
        const int end = pref2[rl];

        const float sn_h = sarr[n * 8 + h];
        float acc  = 0.0f;
        float dsum = 0.0f;

        for (int i = bgn; i < end; i += 8) {
            const int myi  = i + eidx;
            const bool val = (myi < end);
            const int c = lcol[val ? myi : (end - 1)];
            float dv = d[c * 8 + h];
            float v = sn_h + dv;
            v = fmaxf(v, NEG_SLOPE * v);
            v = val ? v : -10000.0f;            // tail -> exp2 = 0
            const float ev = __builtin_amdgcn_exp2f(v);
            dsum += ev;

            #pragma unroll
            for (int k = 0; k < 8; ++k) {
                const int   c_k = __builtin_amdgcn_readlane(c, k * 8);  // SGPR col
                const float e_k = __shfl(ev, k * 8 + oh);
                acc += e_k * bf2f(hb[c_k * 64 + o]);
            }
        }

        dsum += __shfl_xor(dsum, 8, 64);
        dsum += __shfl_xor(dsum, 16, 64);
        dsum += __shfl_xor(dsum, 32, 64);
        float denom = __shfl(dsum, oh);

        const float sn_o = sarr[n * 8 + oh];
        const float dn_o = d[n * 8 + oh];
        float vs = sn_o + dn_o;
        vs = fmaxf(vs, NEG_SLOPE * vs);
        const float es = __builtin_amdgcn_exp2f(vs);
        denom += es;
        acc += es * bf2f(hb[n * 64 + o]);

        out[n * 64 + o] = acc / denom;
    }
}

// ---------------------------------------------------------------------------
extern "C" void kernel_launch(void* const* d_in, const int* in_sizes, int n_in,
                              void* d_out, int out_size, void* d_ws, size_t ws_size,
                              hipStream_t stream) {
    const float* x  = (const float*)d_in[0];
    const int*   ei = (const int*)d_in[1];
    const float* W  = (const float*)d_in[2];
    const float* sa = (const float*)d_in[3];
    const float* da = (const float*)d_in[4];
    float* out = (float*)d_out;
    const int E = in_sizes[1] / 2;

    int NB1 = (E + EPB - 1) / EPB;         // 196 at E=800000
    if (NB1 > 256) NB1 = 256;              // scan width bound (holds for this shape)

    // ws layout
    unsigned short* hb = (unsigned short*)d_ws;     // NN*64 bf16 (6.4 MB)
    float* s  = (float*)(hb + NN * 64);             // NN*8
    float* dd = s + NN * 8;                         // NN*8
    int* S    = (int*)(dd + NN * 8);                // NBUCK*NB1
    int* LP   = S + NBUCK * 256;                    // NBUCK*NB1
    unsigned* tmp = (unsigned*)(LP + NBUCK * 256);  // NB1*EPB (3.2 MB)

    k_fused0<<<GEMM_NB + NB1, 256, 0, stream>>>(x, W, sa, da, ei,
                                                hb, s, dd, S, LP, tmp, E, NB1);
    k_bgather<<<NBUCK * 2, 1024, 0, stream>>>(tmp, S, LP, hb, s, dd, out, NB1);
}

// Round 20
// 67.830 us; speedup vs baseline: 1.1534x; 1.0151x over previous
//
#include <hip/hip_runtime.h>

#define NN 50000
#define NEG_SLOPE 0.2f
#define LOG2E 1.44269504088896340736f

#define GEMM_NB ((NN + 63) / 64)    // 782 gemm blocks
#define NBUCK2 391                  // sub-buckets of 128 rows (ceil(50000/128))
#define EPB 4096                    // edges per scatter block (196 blocks @ E=800K)
#define CAPH 2816                   // sub-bucket cap (mean 2046, sigma 45: +17 sigma)

typedef __bf16 bf16x8 __attribute__((ext_vector_type(8)));
typedef float f32x4 __attribute__((ext_vector_type(4)));

static __device__ __forceinline__ unsigned short f2bf(float f) {
    __bf16 b = (__bf16)f;
    return __builtin_bit_cast(unsigned short, b);
}
static __device__ __forceinline__ float bf2f(unsigned short u) {
    return __uint_as_float(((unsigned)u) << 16);
}

// Per-wave int64-vs-int32 detection: values < 50000, so int64 => all odd
// int32 words of the first 64 pairs are zero. (L1-hit, ~free per wave.)
static __device__ __forceinline__ int detect_i64(const int* __restrict__ ei,
                                                 int lane) {
    unsigned long long b = __ballot(ei[2 * lane + 1] != 0);
    return (b == 0ull) ? 1 : 0;
}

// ---------------------------------------------------------------------------
// FUSED0: blocks [0, GEMM_NB): MFMA GEMM (unchanged, proven);
// blocks [GEMM_NB, GEMM_NB+NB1): per-block edge LDS counting sort by
// SUB-BUCKET (391 bins of 128 rows; 512-bin scan via 2 bins/thread); sorted
// slice written CONTIGUOUSLY to tmp[bx*EPB..] + S/LP matrices. No global
// atomics, no memsets. Record: (row&127)<<24 | col(16b).
__global__ __launch_bounds__(256) void k_fused0(
        const float* __restrict__ x, const float* __restrict__ W,
        const float* __restrict__ sa, const float* __restrict__ da,
        const int* __restrict__ ei,
        unsigned short* __restrict__ hb, float* __restrict__ s,
        float* __restrict__ d, int* __restrict__ S, int* __restrict__ LP,
        unsigned* __restrict__ tmp, int E, int NB1) {
    __shared__ int hist[512];       // sub-bucket counts -> cursors
    __shared__ int pref[256];       // inclusive scan of bin-pairs
    __shared__ unsigned lrec[EPB];  // block-locally sorted records (16 KB)
    const int tid  = threadIdx.x;
    const int lane = tid & 63;

    if (blockIdx.x >= GEMM_NB) {
        // ---- sub-bucket sort path (EPB = 4096 edges/block, 16/thread) ----
        const int bx = blockIdx.x - GEMM_NB;
        hist[tid] = 0; hist[tid + 256] = 0;
        const int f = detect_i64(ei, lane);
        __syncthreads();

        const int base = bx * EPB + tid * 16;
        int rw[16], cl[16];
        const bool fullvec = (base + 16 <= E) && ((E & 3) == 0);
        if (f) {
            if (fullvec) {
                const int4* p = (const int4*)(ei + 2 * base);
                const int4* q = (const int4*)(ei + 2 * E + 2 * base);
                #pragma unroll
                for (int g = 0; g < 8; ++g) {
                    int4 a = p[g]; int4 b = q[g];
                    rw[2 * g] = a.x; rw[2 * g + 1] = a.z;
                    cl[2 * g] = b.x; cl[2 * g + 1] = b.z;
                }
            } else {
                #pragma unroll
                for (int k = 0; k < 16; ++k) {
                    int e = base + k;
                    rw[k] = (e < E) ? ei[2 * e] : -1;
                    cl[k] = (e < E) ? ei[2 * E + 2 * e] : 0;
                }
            }
        } else {
            if (fullvec) {
                const int4* p = (const int4*)(ei + base);
                const int4* q = (const int4*)(ei + E + base);
                #pragma unroll
                for (int g = 0; g < 4; ++g) {
                    int4 a = p[g]; int4 b = q[g];
                    rw[4 * g] = a.x; rw[4 * g + 1] = a.y;
                    rw[4 * g + 2] = a.z; rw[4 * g + 3] = a.w;
                    cl[4 * g] = b.x; cl[4 * g + 1] = b.y;
                    cl[4 * g + 2] = b.z; cl[4 * g + 3] = b.w;
                }
            } else {
                #pragma unroll
                for (int k = 0; k < 16; ++k) {
                    int e = base + k;
                    rw[k] = (e < E) ? ei[e] : -1;
                    cl[k] = (e < E) ? ei[E + e] : 0;
                }
            }
        }

        #pragma unroll
        for (int k = 0; k < 16; ++k)
            if (rw[k] >= 0) atomicAdd(&hist[rw[k] >> 7], 1);
        __syncthreads();

        // scan 512 bins: thread t owns bins 2t, 2t+1
        const int c0 = hist[2 * tid], c1 = hist[2 * tid + 1];
        pref[tid] = c0 + c1;
        __syncthreads();
        for (int off = 1; off < 256; off <<= 1) {
            int u = (tid >= off) ? pref[tid - off] : 0;
            __syncthreads();
            pref[tid] += u;
            __syncthreads();
        }
        const int exBase = pref[tid] - (c0 + c1);
        const int b0 = 2 * tid, b1 = 2 * tid + 1;
        if (b0 < NBUCK2) { S[b0 * NB1 + bx] = c0; LP[b0 * NB1 + bx] = exBase; }
        if (b1 < NBUCK2) { S[b1 * NB1 + bx] = c1; LP[b1 * NB1 + bx] = exBase + c0; }
        hist[b0] = exBase;          // cursors (own bins only -> no hazard)
        hist[b1] = exBase + c0;
        __syncthreads();

        #pragma unroll
        for (int k = 0; k < 16; ++k) {
            if (rw[k] >= 0) {
                int lp = atomicAdd(&hist[rw[k] >> 7], 1);
                lrec[lp] = ((unsigned)rw[k] << 16) | (unsigned)cl[k];
            }
        }
        __syncthreads();

        const int tot = pref[255];
        for (int j = tid; j < tot; j += 256) {
            const unsigned v = lrec[j];
            tmp[bx * EPB + j] = (((v >> 16) & 127u) << 24) | (v & 0xFFFFu);
        }
        return;
    }

    // ---- gemm path (unchanged, proven) ----
    const int wave = tid >> 6;
    const int c    = lane & 15;   // A-row / B-col / C-col within tile
    const int kg   = lane >> 4;   // 0..3 k-group
    const int n0   = blockIdx.x * 64 + wave * 16;

    bf16x8 bf[4][4];
    #pragma unroll
    for (int kt = 0; kt < 4; ++kt) {
        #pragma unroll
        for (int ot = 0; ot < 4; ++ot) {
            const float* wp = &W[(ot * 16 + c) * 128 + kt * 32 + kg * 8];
            f32x4 w0 = *(const f32x4*)wp;
            f32x4 w1 = *(const f32x4*)(wp + 4);
            bf16x8 b;
            #pragma unroll
            for (int j = 0; j < 4; ++j) { b[j] = (__bf16)w0[j]; b[4 + j] = (__bf16)w1[j]; }
            bf[kt][ot] = b;
        }
    }

    int nr = n0 + c; if (nr > NN - 1) nr = NN - 1;
    const float* xp = &x[(long)nr * 128 + kg * 8];

    f32x4 acc[4] = {};
    #pragma unroll
    for (int kt = 0; kt < 4; ++kt) {
        f32x4 x0 = *(const f32x4*)(xp + kt * 32);
        f32x4 x1 = *(const f32x4*)(xp + kt * 32 + 4);
        bf16x8 a;
        #pragma unroll
        for (int j = 0; j < 4; ++j) { a[j] = (__bf16)x0[j]; a[4 + j] = (__bf16)x1[j]; }
        #pragma unroll
        for (int ot = 0; ot < 4; ++ot)
            acc[ot] = __builtin_amdgcn_mfma_f32_16x16x32_bf16(a, bf[kt][ot], acc[ot], 0, 0, 0);
    }

    float sav[4], dav[4];
    #pragma unroll
    for (int ot = 0; ot < 4; ++ot) {
        sav[ot] = sa[ot * 16 + c] * LOG2E;
        dav[ot] = da[ot * 16 + c] * LOG2E;
    }

    const int nodebase = n0 + kg * 4;
    #pragma unroll
    for (int r = 0; r < 4; ++r) {
        const int n = nodebase + r;
        const bool ok = (n < NN);
        if (ok) {
            #pragma unroll
            for (int ot = 0; ot < 4; ++ot) hb[n * 64 + ot * 16 + c] = f2bf(acc[ot][r]);
        }
        float ps[4], pd[4];
        #pragma unroll
        for (int ot = 0; ot < 4; ++ot) { ps[ot] = acc[ot][r] * sav[ot]; pd[ot] = acc[ot][r] * dav[ot]; }
        #pragma unroll
        for (int m = 1; m < 8; m <<= 1) {
            #pragma unroll
            for (int ot = 0; ot < 4; ++ot) {
                ps[ot] += __shfl_xor(ps[ot], m, 64);
                pd[ot] += __shfl_xor(pd[ot], m, 64);
            }
        }
        if (ok && (c & 7) == 0) {
            const int hbid = c >> 3;
            #pragma unroll
            for (int ot = 0; ot < 4; ++ot) {
                s[n * 8 + 2 * ot + hbid] = ps[ot];
                d[n * 8 + 2 * ot + hbid] = pd[ot];
            }
        }
    }
}

// ---------------------------------------------------------------------------
// k_bgather: ONE block per sub-bucket (128 rows), 1024 threads. Stage: thread
// p binary-searches its source slice (8 LDS steps) and copies exactly one
// record, with the 128-bin histogram FUSED into the staging loop (atomic
// overlaps the tmp-load latency). No filtering — every staged record belongs.
// Sort: scan 128 + one scatter pass. Gather: proven (eidx,h) chunk-of-8
// layout — one exp issue per 8 edges x 8 heads, register accumulation.
__global__ __launch_bounds__(1024) void k_bgather(
        const unsigned* __restrict__ tmp, const int* __restrict__ S,
        const int* __restrict__ LP, const unsigned short* __restrict__ hb,
        const float* __restrict__ sarr, const float* __restrict__ d,
        float* __restrict__ out, int NB1) {
    __shared__ int aux2[256];        // inclusive scan of per-source counts
    __shared__ int aux3[256];        // LP per source block
    __shared__ int bins[128];
    __shared__ int pref2[128];
    __shared__ unsigned u_raw[CAPH];
    __shared__ int lcol[CAPH];

    const int t    = threadIdx.x;
    const int bkt  = blockIdx.x;     // sub-bucket: rows [bkt*128, bkt*128+128)
    const int lane = t & 63;
    const int wid  = t >> 6;

    if (t < 256) {
        aux2[t] = (t < NB1) ? S[bkt * NB1 + t] : 0;
        aux3[t] = (t < NB1) ? LP[bkt * NB1 + t] : 0;
    }
    if (t >= 256 && t < 384) bins[t - 256] = 0;
    __syncthreads();
    for (int off = 1; off < 256; off <<= 1) {
        int u = 0;
        if (t < 256 && t >= off) u = aux2[t - off];
        __syncthreads();
        if (t < 256) aux2[t] += u;
        __syncthreads();
    }
    int cnt = aux2[255]; if (cnt > CAPH) cnt = CAPH;

    // parallel staging + fused histogram
    for (int p = t; p < cnt; p += 1024) {
        int lo = 0, hi = 255;
        #pragma unroll
        for (int it = 0; it < 8; ++it) {
            const int mid = (lo + hi) >> 1;
            if (aux2[mid] > p) hi = mid; else lo = mid + 1;
        }
        const int excl = lo ? aux2[lo - 1] : 0;
        const unsigned v = tmp[lo * EPB + aux3[lo] + (p - excl)];
        u_raw[p] = v;
        atomicAdd(&bins[v >> 24], 1);
    }
    __syncthreads();

    const int bv = (t < 128) ? bins[t] : 0;
    if (t < 128) pref2[t] = bv;
    __syncthreads();
    for (int off = 1; off < 128; off <<= 1) {
        int u = 0;
        if (t < 128 && t >= off) u = pref2[t - off];
        __syncthreads();
        if (t < 128) pref2[t] += u;
        __syncthreads();
    }
    if (t < 128) bins[t] = pref2[t] - bv;   // exclusive -> cursors
    __syncthreads();
    for (int i = t; i < cnt; i += 1024) {
        const unsigned v = u_raw[i];
        const int p = atomicAdd(&bins[v >> 24], 1);
        lcol[p] = (int)(v & 0xFFFFu);
    }
    __syncthreads();

    // gather: 128 rows, 8 per wave; lane = eidx*8 + h over chunks of 8 edges.
    const int o    = lane;
    const int oh   = o >> 3;
    const int eidx = lane >> 3;
    const int h    = lane & 7;

    #pragma unroll
    for (int j = 0; j < 8; ++j) {
        const int rl = j * 16 + wid;             // 0..127
        const int n  = bkt * 128 + rl;
        if (n >= NN) continue;

        const int bgn = rl ? pref2[rl - 1] : 0;
        const int end = pref2[rl];

        const float sn_h = sarr[n * 8 + h];
        float acc  = 0.0f;
        float dsum = 0.0f;

        for (int i = bgn; i < end; i += 8) {
            const int myi  = i + eidx;
            const bool val = (myi < end);
            const int c = lcol[val ? myi : (end - 1)];
            float dv = d[c * 8 + h];
            float v = sn_h + dv;
            v = fmaxf(v, NEG_SLOPE * v);
            v = val ? v : -10000.0f;            // tail -> exp2 = 0
            const float ev = __builtin_amdgcn_exp2f(v);
            dsum += ev;

            #pragma unroll
            for (int k = 0; k < 8; ++k) {
                const int   c_k = __builtin_amdgcn_readlane(c, k * 8);  // SGPR col
                const float e_k = __shfl(ev, k * 8 + oh);
                acc += e_k * bf2f(hb[c_k * 64 + o]);
            }
        }

        dsum += __shfl_xor(dsum, 8, 64);
        dsum += __shfl_xor(dsum, 16, 64);
        dsum += __shfl_xor(dsum, 32, 64);
        float denom = __shfl(dsum, oh);

        const float sn_o = sarr[n * 8 + oh];
        const float dn_o = d[n * 8 + oh];
        float vs = sn_o + dn_o;
        vs = fmaxf(vs, NEG_SLOPE * vs);
        const float es = __builtin_amdgcn_exp2f(vs);
        denom += es;
        acc += es * bf2f(hb[n * 64 + o]);

        out[n * 64 + o] = acc / denom;
    }
}

// ---------------------------------------------------------------------------
extern "C" void kernel_launch(void* const* d_in, const int* in_sizes, int n_in,
                              void* d_out, int out_size, void* d_ws, size_t ws_size,
                              hipStream_t stream) {
    const float* x  = (const float*)d_in[0];
    const int*   ei = (const int*)d_in[1];
    const float* W  = (const float*)d_in[2];
    const float* sa = (const float*)d_in[3];
    const float* da = (const float*)d_in[4];
    float* out = (float*)d_out;
    const int E = in_sizes[1] / 2;

    int NB1 = (E + EPB - 1) / EPB;         // 196 at E=800000
    if (NB1 > 256) NB1 = 256;              // scan width bound (holds for this shape)

    // ws layout
    unsigned short* hb = (unsigned short*)d_ws;     // NN*64 bf16 (6.4 MB)
    float* s  = (float*)(hb + NN * 64);             // NN*8
    float* dd = s + NN * 8;                         // NN*8
    int* S    = (int*)(dd + NN * 8);                // NBUCK2*NB1 (~300 KB)
    int* LP   = S + NBUCK2 * 256;                   // NBUCK2*NB1
    unsigned* tmp = (unsigned*)(LP + NBUCK2 * 256); // NB1*EPB (3.2 MB)

    k_fused0<<<GEMM_NB + NB1, 256, 0, stream>>>(x, W, sa, da, ei,
                                                hb, s, dd, S, LP, tmp, E, NB1);
    k_bgather<<<NBUCK2, 1024, 0, stream>>>(tmp, S, LP, hb, s, dd, out, NB1);
}